// Round 1
// baseline (363.679 us; speedup 1.0000x reference)
//
#include <hip/hip_runtime.h>

// avg_voxelize, atomic-free-of-sort version: B=8, C=64, N=65536, r=32
// d_out = [ vox (B*C*r^3 floats) | norm_coords (B*3*N floats) ]
// d_ws  = [ cnt (B*R3 u32, 1 MB) | idx (B*N u16, 1 MB) ]
//
// Pipeline:
//  1. points_kernel : norm_coords out; voxel idx (u16) out; cnt via global atomics
//  2. gather_kernel : one block per (b,c). fp32 acc[32768] in LDS (128 KB);
//     stream feature row coalesced, ds_add_f32 scatter into LDS; then
//     coalesced divide-by-count and store. No sort, no scan, no permutation.

#define BB 8
#define CC 64
#define NN 65536
#define RR 32
#define R3 (RR * RR * RR)          // 32768

__global__ __launch_bounds__(256) void points_kernel(
    const float* __restrict__ coords,      // [B,3,N]
    float* __restrict__ norm_out,          // [B,3,N]
    unsigned int* __restrict__ cnt,        // [B,R3], pre-zeroed
    unsigned short* __restrict__ idx_out)  // [B,N]
{
    int gid = blockIdx.x * 256 + threadIdx.x;   // 0 .. B*N/4 - 1
    int b  = gid >> 14;                         // 16384 threads per batch
    int n4 = (gid & 16383) * 4;                 // 4 points per thread

    const float* cb = coords + (size_t)b * 3 * NN;
    float4 x = *(const float4*)(cb + n4);
    float4 y = *(const float4*)(cb + NN + n4);
    float4 z = *(const float4*)(cb + 2 * NN + n4);

    float4 nx, ny, nz;
    nx.x = fminf(fmaxf(x.x * 32.f, 0.f), 31.f);
    nx.y = fminf(fmaxf(x.y * 32.f, 0.f), 31.f);
    nx.z = fminf(fmaxf(x.z * 32.f, 0.f), 31.f);
    nx.w = fminf(fmaxf(x.w * 32.f, 0.f), 31.f);
    ny.x = fminf(fmaxf(y.x * 32.f, 0.f), 31.f);
    ny.y = fminf(fmaxf(y.y * 32.f, 0.f), 31.f);
    ny.z = fminf(fmaxf(y.z * 32.f, 0.f), 31.f);
    ny.w = fminf(fmaxf(y.w * 32.f, 0.f), 31.f);
    nz.x = fminf(fmaxf(z.x * 32.f, 0.f), 31.f);
    nz.y = fminf(fmaxf(z.y * 32.f, 0.f), 31.f);
    nz.z = fminf(fmaxf(z.z * 32.f, 0.f), 31.f);
    nz.w = fminf(fmaxf(z.w * 32.f, 0.f), 31.f);

    float* nb = norm_out + (size_t)b * 3 * NN;
    *(float4*)(nb + n4)          = nx;
    *(float4*)(nb + NN + n4)     = ny;
    *(float4*)(nb + 2 * NN + n4) = nz;

    // jnp.round = round half to even = rintf (RN mode)
    int i0 = ((int)rintf(nx.x) << 10) | ((int)rintf(ny.x) << 5) | (int)rintf(nz.x);
    int i1 = ((int)rintf(nx.y) << 10) | ((int)rintf(ny.y) << 5) | (int)rintf(nz.y);
    int i2 = ((int)rintf(nx.z) << 10) | ((int)rintf(ny.z) << 5) | (int)rintf(nz.z);
    int i3 = ((int)rintf(nx.w) << 10) | ((int)rintf(ny.w) << 5) | (int)rintf(nz.w);

    unsigned short* ib = idx_out + (size_t)b * NN;
    *(ushort4*)(ib + n4) = make_ushort4((unsigned short)i0, (unsigned short)i1,
                                        (unsigned short)i2, (unsigned short)i3);

    unsigned int* cc = cnt + (size_t)b * R3;
    atomicAdd(&cc[i0], 1u);
    atomicAdd(&cc[i1], 1u);
    atomicAdd(&cc[i2], 1u);
    atomicAdd(&cc[i3], 1u);
}

// One block per (b,c): fp32 LDS accumulator over the full voxel grid.
__global__ __launch_bounds__(1024) void gather_kernel(
    const float* __restrict__ feats,        // [B,C,N]
    const unsigned short* __restrict__ idx, // [B,N]
    const unsigned int* __restrict__ cnt,   // [B,R3]
    float* __restrict__ out)                // [B,C,R3]
{
    __shared__ float acc[R3];               // 128 KB

    int c = blockIdx.x;
    int b = blockIdx.y;
    int t = threadIdx.x;

    // zero accumulator: 8 x float4 per thread, conflict-free
    #pragma unroll
    for (int j = 0; j < 8; j++) {
        *(float4*)(acc + (t + j * 1024) * 4) = make_float4(0.f, 0.f, 0.f, 0.f);
    }
    __syncthreads();

    const float* f = feats + ((size_t)b * CC + c) * NN;
    const unsigned short* I = idx + (size_t)b * NN;

    // 8 points per thread per iteration; coalesced loads, LDS atomic scatter
    #pragma unroll
    for (int it = 0; it < 8; it++) {
        int n0 = (t + it * 1024) * 8;
        float4 f0 = *(const float4*)(f + n0);
        float4 f1 = *(const float4*)(f + n0 + 4);
        ushort4 v0 = *(const ushort4*)(I + n0);
        ushort4 v1 = *(const ushort4*)(I + n0 + 4);
        unsafeAtomicAdd(&acc[v0.x], f0.x);
        unsafeAtomicAdd(&acc[v0.y], f0.y);
        unsafeAtomicAdd(&acc[v0.z], f0.z);
        unsafeAtomicAdd(&acc[v0.w], f0.w);
        unsafeAtomicAdd(&acc[v1.x], f1.x);
        unsafeAtomicAdd(&acc[v1.y], f1.y);
        unsafeAtomicAdd(&acc[v1.z], f1.z);
        unsafeAtomicAdd(&acc[v1.w], f1.w);
    }
    __syncthreads();

    const unsigned int* cb = cnt + (size_t)b * R3;
    float* ob = out + ((size_t)b * CC + c) * R3;
    #pragma unroll
    for (int j = 0; j < 8; j++) {
        int v = (t + j * 1024) * 4;
        float4 s = *(const float4*)(acc + v);
        uint4 cv = *(const uint4*)(cb + v);
        float4 o;
        o.x = __fdividef(s.x, fmaxf((float)cv.x, 1.f));
        o.y = __fdividef(s.y, fmaxf((float)cv.y, 1.f));
        o.z = __fdividef(s.z, fmaxf((float)cv.z, 1.f));
        o.w = __fdividef(s.w, fmaxf((float)cv.w, 1.f));
        *(float4*)(ob + v) = o;
    }
}

extern "C" void kernel_launch(void* const* d_in, const int* in_sizes, int n_in,
                              void* d_out, int out_size, void* d_ws, size_t ws_size,
                              hipStream_t stream) {
    const float* feats  = (const float*)d_in[0];   // [B,C,N]
    const float* coords = (const float*)d_in[1];   // [B,3,N]
    // d_in[2] = resolution (32), hardcoded.

    float* out_vox  = (float*)d_out;                     // B*C*R3
    float* out_norm = out_vox + (size_t)BB * CC * R3;    // B*3*N

    char* ws = (char*)d_ws;
    unsigned int*   cnt = (unsigned int*)ws;                     // 1,048,576 B
    unsigned short* idx = (unsigned short*)(ws + 1048576);       // 1,048,576 B

    hipMemsetAsync(cnt, 0, (size_t)BB * R3 * sizeof(unsigned int), stream);

    points_kernel<<<(BB * NN / 4) / 256, 256, 0, stream>>>(coords, out_norm, cnt, idx);
    gather_kernel<<<dim3(CC, BB), 1024, 0, stream>>>(feats, idx, cnt, out_vox);
}

// Round 4
// 347.385 us; speedup vs baseline: 1.0469x; 1.0469x over previous
//
#include <hip/hip_runtime.h>

// avg_voxelize: B=8, C=64, N=65536, r=32
// d_out = [ vox (B*C*r^3 f32) | norm_coords (B*3*N f32) ]
// d_ws  = [ idx (B*N u16, 1MB) | cnt (B*R3 u32, 1MB) | ghist (64*R3 u16-pairs, 4MB) ]
//
// Pipeline (ZERO global atomics):
//  1. points_kernel : 64 blocks (8 per batch). norm_coords + u16 voxel idx;
//     per-block private LDS u32 histogram (ds_add_u32), flushed as packed u16.
//  2. reduce_kernel : cnt[b][v] = sum of 8 sub-histograms. Plain loads/stores.
//  3. gather_kernel : one block per (b,c). fp32 acc[32768] in LDS (128 KB);
//     stream feature row coalesced, ds_add_f32 (unsafeAtomicAdd) scatter;
//     divide by cnt, coalesced f32 store. [proven in round 1: 188us, 3.9e-3]

#define BB 8
#define CC 64
#define NN 65536
#define RR 32
#define R3 (RR * RR * RR)          // 32768
#define NSUB 8                     // histogram sub-blocks per batch
#define PTS_PER_BLK (NN / NSUB)    // 8192

__global__ __launch_bounds__(1024) void points_kernel(
    const float* __restrict__ coords,      // [B,3,N]
    float* __restrict__ norm_out,          // [B,3,N]
    unsigned short* __restrict__ idx_out,  // [B,N]
    unsigned int* __restrict__ ghist)      // [64][R3/2] packed u16 pairs
{
    __shared__ unsigned int hist[R3];      // 128 KB private histogram
    int blk = blockIdx.x;                  // 0..63
    int b = blk >> 3;
    int s = blk & 7;
    int t = threadIdx.x;

    #pragma unroll
    for (int k = 0; k < 8; k++)
        *(uint4*)(hist + 4 * (t + k * 1024)) = make_uint4(0u, 0u, 0u, 0u);
    __syncthreads();

    const float* cb = coords + (size_t)b * 3 * NN;
    float* nb = norm_out + (size_t)b * 3 * NN;
    unsigned short* ib = idx_out + (size_t)b * NN;

    #pragma unroll
    for (int p = 0; p < 2; p++) {
        int n = s * PTS_PER_BLK + (t + p * 1024) * 4;
        float4 x = *(const float4*)(cb + n);
        float4 y = *(const float4*)(cb + NN + n);
        float4 z = *(const float4*)(cb + 2 * NN + n);

        float4 nx, ny, nz;
        nx.x = fminf(fmaxf(x.x * 32.f, 0.f), 31.f);
        nx.y = fminf(fmaxf(x.y * 32.f, 0.f), 31.f);
        nx.z = fminf(fmaxf(x.z * 32.f, 0.f), 31.f);
        nx.w = fminf(fmaxf(x.w * 32.f, 0.f), 31.f);
        ny.x = fminf(fmaxf(y.x * 32.f, 0.f), 31.f);
        ny.y = fminf(fmaxf(y.y * 32.f, 0.f), 31.f);
        ny.z = fminf(fmaxf(y.z * 32.f, 0.f), 31.f);
        ny.w = fminf(fmaxf(y.w * 32.f, 0.f), 31.f);
        nz.x = fminf(fmaxf(z.x * 32.f, 0.f), 31.f);
        nz.y = fminf(fmaxf(z.y * 32.f, 0.f), 31.f);
        nz.z = fminf(fmaxf(z.z * 32.f, 0.f), 31.f);
        nz.w = fminf(fmaxf(z.w * 32.f, 0.f), 31.f);

        *(float4*)(nb + n)          = nx;
        *(float4*)(nb + NN + n)     = ny;
        *(float4*)(nb + 2 * NN + n) = nz;

        // jnp.round = round half to even = rintf (RN mode)
        int i0 = ((int)rintf(nx.x) << 10) | ((int)rintf(ny.x) << 5) | (int)rintf(nz.x);
        int i1 = ((int)rintf(nx.y) << 10) | ((int)rintf(ny.y) << 5) | (int)rintf(nz.y);
        int i2 = ((int)rintf(nx.z) << 10) | ((int)rintf(ny.z) << 5) | (int)rintf(nz.z);
        int i3 = ((int)rintf(nx.w) << 10) | ((int)rintf(ny.w) << 5) | (int)rintf(nz.w);

        *(ushort4*)(ib + n) = make_ushort4((unsigned short)i0, (unsigned short)i1,
                                           (unsigned short)i2, (unsigned short)i3);

        atomicAdd(&hist[i0], 1u);
        atomicAdd(&hist[i1], 1u);
        atomicAdd(&hist[i2], 1u);
        atomicAdd(&hist[i3], 1u);
    }
    __syncthreads();

    // flush as packed u16 pairs (counts <= 8192 fit u16)
    unsigned int* gh = ghist + (size_t)blk * (R3 / 2);
    #pragma unroll
    for (int k = 0; k < 16; k++) {
        int w = t + k * 1024;
        uint2 u = *(const uint2*)(hist + 2 * w);
        gh[w] = u.x | (u.y << 16);
    }
}

__global__ __launch_bounds__(256) void reduce_kernel(
    const unsigned int* __restrict__ ghist,  // [64][R3/2]
    unsigned int* __restrict__ cnt)          // [B][R3]
{
    int gid = blockIdx.x * 256 + threadIdx.x;   // 0 .. B*R3/2 - 1
    int b = gid >> 14;                          // / 16384
    int w = gid & 16383;
    unsigned s0 = 0, s1 = 0;
    #pragma unroll
    for (int k = 0; k < 8; k++) {
        unsigned u = ghist[(size_t)(b * 8 + k) * (R3 / 2) + w];
        s0 += u & 0xFFFFu;
        s1 += u >> 16;
    }
    *(uint2*)(cnt + (size_t)b * R3 + 2 * w) = make_uint2(s0, s1);
}

// One block per (b,c): fp32 LDS accumulator over the full voxel grid.
__global__ __launch_bounds__(1024) void gather_kernel(
    const float* __restrict__ feats,        // [B,C,N]
    const unsigned short* __restrict__ idx, // [B,N]
    const unsigned int* __restrict__ cnt,   // [B,R3]
    float* __restrict__ out)                // [B,C,R3]
{
    __shared__ float acc[R3];               // 128 KB

    int c = blockIdx.x;
    int b = blockIdx.y;
    int t = threadIdx.x;

    // zero accumulator: 8 x float4 per thread, conflict-free
    #pragma unroll
    for (int j = 0; j < 8; j++) {
        *(float4*)(acc + (t + j * 1024) * 4) = make_float4(0.f, 0.f, 0.f, 0.f);
    }
    __syncthreads();

    const float* f = feats + ((size_t)b * CC + c) * NN;
    const unsigned short* I = idx + (size_t)b * NN;

    // 8 points per thread per iteration; coalesced loads, LDS atomic scatter
    #pragma unroll
    for (int it = 0; it < 8; it++) {
        int n0 = (t + it * 1024) * 8;
        float4 f0 = *(const float4*)(f + n0);
        float4 f1 = *(const float4*)(f + n0 + 4);
        ushort4 v0 = *(const ushort4*)(I + n0);
        ushort4 v1 = *(const ushort4*)(I + n0 + 4);
        unsafeAtomicAdd(&acc[v0.x], f0.x);
        unsafeAtomicAdd(&acc[v0.y], f0.y);
        unsafeAtomicAdd(&acc[v0.z], f0.z);
        unsafeAtomicAdd(&acc[v0.w], f0.w);
        unsafeAtomicAdd(&acc[v1.x], f1.x);
        unsafeAtomicAdd(&acc[v1.y], f1.y);
        unsafeAtomicAdd(&acc[v1.z], f1.z);
        unsafeAtomicAdd(&acc[v1.w], f1.w);
    }
    __syncthreads();

    const unsigned int* cb = cnt + (size_t)b * R3;
    float* ob = out + ((size_t)b * CC + c) * R3;
    #pragma unroll
    for (int j = 0; j < 8; j++) {
        int v = (t + j * 1024) * 4;
        float4 s = *(const float4*)(acc + v);
        uint4 cv = *(const uint4*)(cb + v);
        float4 o;
        o.x = __fdividef(s.x, fmaxf((float)cv.x, 1.f));
        o.y = __fdividef(s.y, fmaxf((float)cv.y, 1.f));
        o.z = __fdividef(s.z, fmaxf((float)cv.z, 1.f));
        o.w = __fdividef(s.w, fmaxf((float)cv.w, 1.f));
        *(float4*)(ob + v) = o;
    }
}

extern "C" void kernel_launch(void* const* d_in, const int* in_sizes, int n_in,
                              void* d_out, int out_size, void* d_ws, size_t ws_size,
                              hipStream_t stream) {
    const float* feats  = (const float*)d_in[0];   // [B,C,N]
    const float* coords = (const float*)d_in[1];   // [B,3,N]
    // d_in[2] = resolution (32), hardcoded.

    float* out_vox  = (float*)d_out;                     // B*C*R3
    float* out_norm = out_vox + (size_t)BB * CC * R3;    // B*3*N

    char* ws = (char*)d_ws;
    unsigned short* idx   = (unsigned short*)ws;                 // 1 MB
    unsigned int*   cnt   = (unsigned int*)(ws + (1 << 20));     // 1 MB
    unsigned int*   ghist = (unsigned int*)(ws + (2 << 20));     // 4 MB

    points_kernel<<<BB * NSUB, 1024, 0, stream>>>(coords, out_norm, idx, ghist);
    reduce_kernel<<<(BB * R3 / 2) / 256, 256, 0, stream>>>(ghist, cnt);
    gather_kernel<<<dim3(CC, BB), 1024, 0, stream>>>(feats, idx, cnt, out_vox);
}

// Round 5
// 286.886 us; speedup vs baseline: 1.2677x; 1.2109x over previous
//
#include <hip/hip_runtime.h>
#include <hip/hip_bf16.h>

// avg_voxelize: B=8, C=64, N=65536, r=32
// d_out = [ vox (B*C*r^3 f32) | norm_coords (B*3*N f32) ]
// d_ws  = [ ghist (32*R3 u16-pairs, 2MB) | packed->pos (B*N u32, 2MB) | off (B*R3 u32, 1MB) ]
//
// Counting sort with ZERO global atomics:
//  1. points_kernel : 32 blocks (4/batch). norm_coords; LDS u32 histogram;
//     rank = ds_add_rtn; packed[n] = (v<<14)|rank; flush hist as u16 pairs.
//  2. scan_kernel   : 8 blocks (1/batch). In-place exclusive prefix over the 4
//     sub-hists per voxel (u16), per-batch exclusive scan of totals -> off.
//  3. pos_kernel    : pos[n] = off[v] + sbase[s][v] + rank (in-place over packed).
//  4. gather_kernel : per (b,c): scatter feature row to sorted order in LDS
//     (bf16, plain ds_write), segmented-sum contiguous runs, coalesced store.
//     [round-0 proven: 96us/dispatch, no atomics]

#define BB 8
#define CC 64
#define NN 65536
#define RR 32
#define R3 (RR * RR * RR)          // 32768
#define NSUB 4                     // sub-blocks per batch
#define PTS (NN / NSUB)            // 16384 points per sub-block
#define HWORDS (R3 / 2)            // 16384 packed u16-pair words per sub-hist

__global__ __launch_bounds__(1024) void points_kernel(
    const float* __restrict__ coords,      // [B,3,N]
    float* __restrict__ norm_out,          // [B,3,N]
    unsigned int* __restrict__ packed,     // [B,N]: (v<<14)|rank
    unsigned int* __restrict__ ghist)      // [32][HWORDS] u16 pairs
{
    __shared__ unsigned int hist[R3];      // 128 KB private histogram
    int blk = blockIdx.x;                  // 0..31
    int b = blk >> 2;
    int s = blk & 3;
    int t = threadIdx.x;

    #pragma unroll
    for (int k = 0; k < 8; k++)
        *(uint4*)(hist + 4 * (t + k * 1024)) = make_uint4(0u, 0u, 0u, 0u);
    __syncthreads();

    const float* cb = coords + (size_t)b * 3 * NN;
    float* nb = norm_out + (size_t)b * 3 * NN;
    unsigned int* pb = packed + (size_t)b * NN;

    #pragma unroll
    for (int p = 0; p < 4; p++) {
        int n = s * PTS + (t + p * 1024) * 4;
        float4 x = *(const float4*)(cb + n);
        float4 y = *(const float4*)(cb + NN + n);
        float4 z = *(const float4*)(cb + 2 * NN + n);

        float4 nx, ny, nz;
        nx.x = fminf(fmaxf(x.x * 32.f, 0.f), 31.f);
        nx.y = fminf(fmaxf(x.y * 32.f, 0.f), 31.f);
        nx.z = fminf(fmaxf(x.z * 32.f, 0.f), 31.f);
        nx.w = fminf(fmaxf(x.w * 32.f, 0.f), 31.f);
        ny.x = fminf(fmaxf(y.x * 32.f, 0.f), 31.f);
        ny.y = fminf(fmaxf(y.y * 32.f, 0.f), 31.f);
        ny.z = fminf(fmaxf(y.z * 32.f, 0.f), 31.f);
        ny.w = fminf(fmaxf(y.w * 32.f, 0.f), 31.f);
        nz.x = fminf(fmaxf(z.x * 32.f, 0.f), 31.f);
        nz.y = fminf(fmaxf(z.y * 32.f, 0.f), 31.f);
        nz.z = fminf(fmaxf(z.z * 32.f, 0.f), 31.f);
        nz.w = fminf(fmaxf(z.w * 32.f, 0.f), 31.f);

        *(float4*)(nb + n)          = nx;
        *(float4*)(nb + NN + n)     = ny;
        *(float4*)(nb + 2 * NN + n) = nz;

        // jnp.round = round half to even = rintf (RN mode)
        int i0 = ((int)rintf(nx.x) << 10) | ((int)rintf(ny.x) << 5) | (int)rintf(nz.x);
        int i1 = ((int)rintf(nx.y) << 10) | ((int)rintf(ny.y) << 5) | (int)rintf(nz.y);
        int i2 = ((int)rintf(nx.z) << 10) | ((int)rintf(ny.z) << 5) | (int)rintf(nz.z);
        int i3 = ((int)rintf(nx.w) << 10) | ((int)rintf(ny.w) << 5) | (int)rintf(nz.w);

        unsigned int r0 = atomicAdd(&hist[i0], 1u);   // rank < 16384
        unsigned int r1 = atomicAdd(&hist[i1], 1u);
        unsigned int r2 = atomicAdd(&hist[i2], 1u);
        unsigned int r3 = atomicAdd(&hist[i3], 1u);

        *(uint4*)(pb + n) = make_uint4(((unsigned)i0 << 14) | r0,
                                       ((unsigned)i1 << 14) | r1,
                                       ((unsigned)i2 << 14) | r2,
                                       ((unsigned)i3 << 14) | r3);
    }
    __syncthreads();

    // flush as packed u16 pairs (counts <= 16384 fit u16)
    unsigned int* gh = ghist + (size_t)blk * HWORDS;
    #pragma unroll
    for (int k = 0; k < 16; k++) {
        int w = t + k * 1024;
        uint2 u = *(const uint2*)(hist + 2 * w);
        gh[w] = u.x | (u.y << 16);
    }
}

// One block per batch. In-place: ghist slot s becomes prefix-before-s (u16).
// off[b][v] = batch-wide exclusive prefix of total counts.
__global__ __launch_bounds__(1024) void scan_kernel(
    unsigned int* __restrict__ ghist,      // [32][HWORDS], in-place -> sbase
    unsigned int* __restrict__ off)        // [B][R3]
{
    int b = blockIdx.x;
    int t = threadIdx.x;

    unsigned int cnt_lo[16], cnt_hi[16];
    unsigned int tsum = 0;
    #pragma unroll
    for (int k = 0; k < 16; k++) {
        int w = t * 16 + k;
        unsigned int lo = 0, hi = 0;
        #pragma unroll
        for (int s = 0; s < NSUB; s++) {
            unsigned int* p = ghist + (size_t)(b * NSUB + s) * HWORDS + w;
            unsigned int u = *p;
            *p = lo | (hi << 16);          // prefix before s
            lo += u & 0xFFFFu;
            hi += u >> 16;
        }
        cnt_lo[k] = lo;                    // total count voxel 2w
        cnt_hi[k] = hi;                    // total count voxel 2w+1
        tsum += lo + hi;
    }

    __shared__ unsigned int aux[1024];
    aux[t] = tsum;
    __syncthreads();
    // Hillis-Steele inclusive scan over 1024 partials
    for (int d = 1; d < 1024; d <<= 1) {
        unsigned int v = (t >= d) ? aux[t - d] : 0u;
        __syncthreads();
        aux[t] += v;
        __syncthreads();
    }
    unsigned int run = (t == 0) ? 0u : aux[t - 1];

    unsigned int* O = off + (size_t)b * R3;
    #pragma unroll
    for (int k = 0; k < 16; k++) {
        int v = t * 32 + 2 * k;
        *(uint2*)(O + v) = make_uint2(run, run + cnt_lo[k]);
        run += cnt_lo[k] + cnt_hi[k];
    }
}

// pos[n] = off[v] + sbase[s][v] + rank, written in-place over packed.
__global__ __launch_bounds__(256) void pos_kernel(
    unsigned int* __restrict__ packed,     // [B,N] in: (v<<14)|rank, out: pos
    const unsigned int* __restrict__ off,  // [B][R3]
    const unsigned int* __restrict__ ghist)// [32][HWORDS] = sbase u16 pairs
{
    int gid = blockIdx.x * 256 + threadIdx.x;   // 0 .. B*N/4 - 1
    int b  = gid >> 14;                         // 16384 threads per batch
    int n4 = (gid & 16383) * 4;
    int s  = n4 >> 14;                          // sub-block (n4 / PTS)

    unsigned int* pb = packed + (size_t)b * NN + n4;
    const unsigned int* O = off + (size_t)b * R3;
    const unsigned int* G = ghist + (size_t)(b * NSUB + s) * HWORDS;

    uint4 pk = *(uint4*)pb;
    {
        unsigned v = pk.x >> 14, r = pk.x & 16383u;
        unsigned u = G[v >> 1];
        pk.x = O[v] + ((v & 1) ? (u >> 16) : (u & 0xFFFFu)) + r;
    }
    {
        unsigned v = pk.y >> 14, r = pk.y & 16383u;
        unsigned u = G[v >> 1];
        pk.y = O[v] + ((v & 1) ? (u >> 16) : (u & 0xFFFFu)) + r;
    }
    {
        unsigned v = pk.z >> 14, r = pk.z & 16383u;
        unsigned u = G[v >> 1];
        pk.z = O[v] + ((v & 1) ? (u >> 16) : (u & 0xFFFFu)) + r;
    }
    {
        unsigned v = pk.w >> 14, r = pk.w & 16383u;
        unsigned u = G[v >> 1];
        pk.w = O[v] + ((v & 1) ? (u >> 16) : (u & 0xFFFFu)) + r;
    }
    *(uint4*)pb = pk;
}

// One block per (b,c): scatter to sorted order in LDS (bf16), segmented sum.
__global__ __launch_bounds__(1024) void gather_kernel(
    const float* __restrict__ feats,        // [B,C,N]
    const unsigned int* __restrict__ pos,   // [B,N]
    const unsigned int* __restrict__ off,   // [B][R3]
    float* __restrict__ out)                // [B,C,R3]
{
    __shared__ __hip_bfloat16 srt[NN];      // 128 KB

    int c = blockIdx.x;
    int b = blockIdx.y;
    int t = threadIdx.x;

    const float* f = feats + ((size_t)b * CC + c) * NN;
    const unsigned int* P = pos + (size_t)b * NN;

    // 16 iterations: 1024 threads x (float4 + uint4); random LDS b16 writes
    for (int n0 = t * 4; n0 < NN; n0 += 1024 * 4) {
        float4 fv = *(const float4*)(f + n0);
        uint4 pv = *(const uint4*)(P + n0);
        srt[pv.x] = __float2bfloat16(fv.x);
        srt[pv.y] = __float2bfloat16(fv.y);
        srt[pv.z] = __float2bfloat16(fv.z);
        srt[pv.w] = __float2bfloat16(fv.w);
    }
    __syncthreads();

    const unsigned int* O = off + (size_t)b * R3;
    float* ob = out + ((size_t)b * CC + c) * R3;
    for (int j = 0; j < 32; j++) {
        int v = t + j * 1024;
        unsigned int s0 = O[v];
        unsigned int s1 = (v < R3 - 1) ? O[v + 1] : (unsigned)NN;
        float s = 0.0f;
        for (unsigned int p = s0; p < s1; p++) s += __bfloat162float(srt[p]);
        ob[v] = __fdividef(s, fmaxf((float)(s1 - s0), 1.0f));
    }
}

extern "C" void kernel_launch(void* const* d_in, const int* in_sizes, int n_in,
                              void* d_out, int out_size, void* d_ws, size_t ws_size,
                              hipStream_t stream) {
    const float* feats  = (const float*)d_in[0];   // [B,C,N]
    const float* coords = (const float*)d_in[1];   // [B,3,N]
    // d_in[2] = resolution (32), hardcoded.

    float* out_vox  = (float*)d_out;                     // B*C*R3
    float* out_norm = out_vox + (size_t)BB * CC * R3;    // B*3*N

    char* ws = (char*)d_ws;
    unsigned int* ghist  = (unsigned int*)ws;                    // 2 MB
    unsigned int* packed = (unsigned int*)(ws + (2 << 20));      // 2 MB (becomes pos)
    unsigned int* off    = (unsigned int*)(ws + (4 << 20));      // 1 MB

    points_kernel<<<BB * NSUB, 1024, 0, stream>>>(coords, out_norm, packed, ghist);
    scan_kernel<<<BB, 1024, 0, stream>>>(ghist, off);
    pos_kernel<<<(BB * NN / 4) / 256, 256, 0, stream>>>(packed, off, ghist);
    gather_kernel<<<dim3(CC, BB), 1024, 0, stream>>>(feats, packed, off, out_vox);
}

// Round 6
// 284.229 us; speedup vs baseline: 1.2795x; 1.0093x over previous
//
#include <hip/hip_runtime.h>
#include <hip/hip_bf16.h>

// avg_voxelize: B=8, C=64, N=65536, r=32
// d_out = [ vox (B*C*r^3 f32) | norm_coords (B*3*N f32) ]
// d_ws  = [ ghist (32*R3 u16-pairs, 2MB) | packed->pos (B*N u32, 2MB) | off (B*R3 u32, 1MB) ]
//
// Counting sort with ZERO global atomics:
//  1. points_kernel : 32 blocks (4/batch). norm_coords; LDS u32 histogram;
//     rank = ds_add_rtn; packed[n] = (v<<14)|rank; flush hist as u16 pairs.
//  2. scan_kernel   : 8 blocks (1/batch). In-place exclusive prefix over the 4
//     sub-hists per voxel (uint4-vectorized RMW), per-batch scan -> off.
//  3. pos_kernel    : pos[n] = off[v] + sbase[s][v] + rank (in-place over packed).
//  4. gather_kernel : per (b,c): scatter feature row to sorted order in LDS
//     (bf16, plain ds_write); segment sum via FIXED 8-element masked window
//     (4 independent ds_read_b32 -> one latency exposure per voxel) + rare
//     fallback loop for runs > 8. Coalesced store.

#define BB 8
#define CC 64
#define NN 65536
#define RR 32
#define R3 (RR * RR * RR)          // 32768
#define NSUB 4                     // sub-blocks per batch
#define PTS (NN / NSUB)            // 16384 points per sub-block
#define HWORDS (R3 / 2)            // 16384 packed u16-pair words per sub-hist

__global__ __launch_bounds__(1024) void points_kernel(
    const float* __restrict__ coords,      // [B,3,N]
    float* __restrict__ norm_out,          // [B,3,N]
    unsigned int* __restrict__ packed,     // [B,N]: (v<<14)|rank
    unsigned int* __restrict__ ghist)      // [32][HWORDS] u16 pairs
{
    __shared__ unsigned int hist[R3];      // 128 KB private histogram
    int blk = blockIdx.x;                  // 0..31
    int b = blk >> 2;
    int s = blk & 3;
    int t = threadIdx.x;

    #pragma unroll
    for (int k = 0; k < 8; k++)
        *(uint4*)(hist + 4 * (t + k * 1024)) = make_uint4(0u, 0u, 0u, 0u);
    __syncthreads();

    const float* cb = coords + (size_t)b * 3 * NN;
    float* nb = norm_out + (size_t)b * 3 * NN;
    unsigned int* pb = packed + (size_t)b * NN;

    #pragma unroll
    for (int p = 0; p < 4; p++) {
        int n = s * PTS + (t + p * 1024) * 4;
        float4 x = *(const float4*)(cb + n);
        float4 y = *(const float4*)(cb + NN + n);
        float4 z = *(const float4*)(cb + 2 * NN + n);

        float4 nx, ny, nz;
        nx.x = fminf(fmaxf(x.x * 32.f, 0.f), 31.f);
        nx.y = fminf(fmaxf(x.y * 32.f, 0.f), 31.f);
        nx.z = fminf(fmaxf(x.z * 32.f, 0.f), 31.f);
        nx.w = fminf(fmaxf(x.w * 32.f, 0.f), 31.f);
        ny.x = fminf(fmaxf(y.x * 32.f, 0.f), 31.f);
        ny.y = fminf(fmaxf(y.y * 32.f, 0.f), 31.f);
        ny.z = fminf(fmaxf(y.z * 32.f, 0.f), 31.f);
        ny.w = fminf(fmaxf(y.w * 32.f, 0.f), 31.f);
        nz.x = fminf(fmaxf(z.x * 32.f, 0.f), 31.f);
        nz.y = fminf(fmaxf(z.y * 32.f, 0.f), 31.f);
        nz.z = fminf(fmaxf(z.z * 32.f, 0.f), 31.f);
        nz.w = fminf(fmaxf(z.w * 32.f, 0.f), 31.f);

        *(float4*)(nb + n)          = nx;
        *(float4*)(nb + NN + n)     = ny;
        *(float4*)(nb + 2 * NN + n) = nz;

        // jnp.round = round half to even = rintf (RN mode)
        int i0 = ((int)rintf(nx.x) << 10) | ((int)rintf(ny.x) << 5) | (int)rintf(nz.x);
        int i1 = ((int)rintf(nx.y) << 10) | ((int)rintf(ny.y) << 5) | (int)rintf(nz.y);
        int i2 = ((int)rintf(nx.z) << 10) | ((int)rintf(ny.z) << 5) | (int)rintf(nz.z);
        int i3 = ((int)rintf(nx.w) << 10) | ((int)rintf(ny.w) << 5) | (int)rintf(nz.w);

        unsigned int r0 = atomicAdd(&hist[i0], 1u);   // rank < 16384
        unsigned int r1 = atomicAdd(&hist[i1], 1u);
        unsigned int r2 = atomicAdd(&hist[i2], 1u);
        unsigned int r3 = atomicAdd(&hist[i3], 1u);

        *(uint4*)(pb + n) = make_uint4(((unsigned)i0 << 14) | r0,
                                       ((unsigned)i1 << 14) | r1,
                                       ((unsigned)i2 << 14) | r2,
                                       ((unsigned)i3 << 14) | r3);
    }
    __syncthreads();

    // flush as packed u16 pairs (counts <= 16384 fit u16)
    unsigned int* gh = ghist + (size_t)blk * HWORDS;
    #pragma unroll
    for (int k = 0; k < 16; k++) {
        int w = t + k * 1024;
        uint2 u = *(const uint2*)(hist + 2 * w);
        gh[w] = u.x | (u.y << 16);
    }
}

// One block per batch. In-place: ghist slot s becomes prefix-before-s (u16).
// off[b][v] = batch-wide exclusive prefix of total counts.
// uint4-vectorized RMW: 16 loads + 16 stores per thread, full MLP.
__global__ __launch_bounds__(1024) void scan_kernel(
    unsigned int* __restrict__ ghist,      // [32][HWORDS], in-place -> sbase
    unsigned int* __restrict__ off)        // [B][R3]
{
    int b = blockIdx.x;
    int t = threadIdx.x;

    uint4 u[NSUB][4];
    #pragma unroll
    for (int s = 0; s < NSUB; s++) {
        const unsigned int* p = ghist + (size_t)(b * NSUB + s) * HWORDS + t * 16;
        #pragma unroll
        for (int k = 0; k < 4; k++) u[s][k] = *(const uint4*)(p + 4 * k);
    }

    unsigned plo[16], phi[16];
    #pragma unroll
    for (int w = 0; w < 16; w++) { plo[w] = 0u; phi[w] = 0u; }

    #pragma unroll
    for (int s = 0; s < NSUB; s++) {
        #pragma unroll
        for (int k = 0; k < 4; k++) {
            uint4 val = u[s][k];
            uint4 rep;
            rep.x = plo[4*k+0] | (phi[4*k+0] << 16); plo[4*k+0] += val.x & 0xFFFFu; phi[4*k+0] += val.x >> 16;
            rep.y = plo[4*k+1] | (phi[4*k+1] << 16); plo[4*k+1] += val.y & 0xFFFFu; phi[4*k+1] += val.y >> 16;
            rep.z = plo[4*k+2] | (phi[4*k+2] << 16); plo[4*k+2] += val.z & 0xFFFFu; phi[4*k+2] += val.z >> 16;
            rep.w = plo[4*k+3] | (phi[4*k+3] << 16); plo[4*k+3] += val.w & 0xFFFFu; phi[4*k+3] += val.w >> 16;
            u[s][k] = rep;
        }
    }

    #pragma unroll
    for (int s = 0; s < NSUB; s++) {
        unsigned int* p = ghist + (size_t)(b * NSUB + s) * HWORDS + t * 16;
        #pragma unroll
        for (int k = 0; k < 4; k++) *(uint4*)(p + 4 * k) = u[s][k];
    }

    unsigned tsum = 0;
    #pragma unroll
    for (int w = 0; w < 16; w++) tsum += plo[w] + phi[w];

    __shared__ unsigned int aux[1024];
    aux[t] = tsum;
    __syncthreads();
    // Hillis-Steele inclusive scan over 1024 partials
    for (int d = 1; d < 1024; d <<= 1) {
        unsigned int vv = (t >= d) ? aux[t - d] : 0u;
        __syncthreads();
        aux[t] += vv;
        __syncthreads();
    }
    unsigned run = (t == 0) ? 0u : aux[t - 1];

    unsigned int* O = off + (size_t)b * R3;
    #pragma unroll
    for (int w = 0; w < 16; w++) {
        int v = t * 32 + 2 * w;
        *(uint2*)(O + v) = make_uint2(run, run + plo[w]);
        run += plo[w] + phi[w];
    }
}

// pos[n] = off[v] + sbase[s][v] + rank, written in-place over packed.
__global__ __launch_bounds__(256) void pos_kernel(
    unsigned int* __restrict__ packed,     // [B,N] in: (v<<14)|rank, out: pos
    const unsigned int* __restrict__ off,  // [B][R3]
    const unsigned int* __restrict__ ghist)// [32][HWORDS] = sbase u16 pairs
{
    int gid = blockIdx.x * 256 + threadIdx.x;   // 0 .. B*N/4 - 1
    int b  = gid >> 14;                         // 16384 threads per batch
    int n4 = (gid & 16383) * 4;
    int s  = n4 >> 14;                          // sub-block (n4 / PTS)

    unsigned int* pb = packed + (size_t)b * NN + n4;
    const unsigned int* O = off + (size_t)b * R3;
    const unsigned int* G = ghist + (size_t)(b * NSUB + s) * HWORDS;

    uint4 pk = *(uint4*)pb;
    {
        unsigned v = pk.x >> 14, r = pk.x & 16383u;
        unsigned u = G[v >> 1];
        pk.x = O[v] + ((v & 1) ? (u >> 16) : (u & 0xFFFFu)) + r;
    }
    {
        unsigned v = pk.y >> 14, r = pk.y & 16383u;
        unsigned u = G[v >> 1];
        pk.y = O[v] + ((v & 1) ? (u >> 16) : (u & 0xFFFFu)) + r;
    }
    {
        unsigned v = pk.z >> 14, r = pk.z & 16383u;
        unsigned u = G[v >> 1];
        pk.z = O[v] + ((v & 1) ? (u >> 16) : (u & 0xFFFFu)) + r;
    }
    {
        unsigned v = pk.w >> 14, r = pk.w & 16383u;
        unsigned u = G[v >> 1];
        pk.w = O[v] + ((v & 1) ? (u >> 16) : (u & 0xFFFFu)) + r;
    }
    *(uint4*)pb = pk;
}

// One block per (b,c): scatter to sorted order in LDS (bf16), then segment
// sum via fixed 8-element masked window (4 independent b32 reads per voxel).
__global__ __launch_bounds__(1024) void gather_kernel(
    const float* __restrict__ feats,        // [B,C,N]
    const unsigned int* __restrict__ pos,   // [B,N]
    const unsigned int* __restrict__ off,   // [B][R3]
    float* __restrict__ out)                // [B,C,R3]
{
    __shared__ __hip_bfloat16 srt[NN];      // 128 KB

    int c = blockIdx.x;
    int b = blockIdx.y;
    int t = threadIdx.x;

    const float* f = feats + ((size_t)b * CC + c) * NN;
    const unsigned int* P = pos + (size_t)b * NN;

    // 16 iterations: 1024 threads x (float4 + uint4); random LDS b16 writes
    for (int n0 = t * 4; n0 < NN; n0 += 1024 * 4) {
        float4 fv = *(const float4*)(f + n0);
        uint4 pv = *(const uint4*)(P + n0);
        srt[pv.x] = __float2bfloat16(fv.x);
        srt[pv.y] = __float2bfloat16(fv.y);
        srt[pv.z] = __float2bfloat16(fv.z);
        srt[pv.w] = __float2bfloat16(fv.w);
    }
    __syncthreads();

    const unsigned int* W = (const unsigned int*)srt;   // bf16 pairs
    const unsigned int* O = off + (size_t)b * R3;
    float* ob = out + ((size_t)b * CC + c) * R3;
    const unsigned WMAX = NN / 2 - 1;

    for (int j = 0; j < 32; j++) {
        int v = t + j * 1024;
        unsigned s0 = O[v];
        unsigned s1 = (v < R3 - 1) ? O[v + 1] : (unsigned)NN;
        unsigned w0 = s0 >> 1;
        unsigned base = w0 << 1;

        // 4 independent LDS b32 reads covering positions [base, base+8)
        unsigned u0 = W[w0     < WMAX ? w0     : WMAX];
        unsigned u1 = W[w0 + 1 < WMAX ? w0 + 1 : WMAX];
        unsigned u2 = W[w0 + 2 < WMAX ? w0 + 2 : WMAX];
        unsigned u3 = W[w0 + 3 < WMAX ? w0 + 3 : WMAX];

        float s = 0.f;
        float e;
        e = __uint_as_float(u0 << 16);         s += (base     >= s0 && base     < s1) ? e : 0.f;
        e = __uint_as_float(u0 & 0xffff0000u); s += (base + 1 < s1) ? e : 0.f;
        e = __uint_as_float(u1 << 16);         s += (base + 2 < s1) ? e : 0.f;
        e = __uint_as_float(u1 & 0xffff0000u); s += (base + 3 < s1) ? e : 0.f;
        e = __uint_as_float(u2 << 16);         s += (base + 4 < s1) ? e : 0.f;
        e = __uint_as_float(u2 & 0xffff0000u); s += (base + 5 < s1) ? e : 0.f;
        e = __uint_as_float(u3 << 16);         s += (base + 6 < s1) ? e : 0.f;
        e = __uint_as_float(u3 & 0xffff0000u); s += (base + 7 < s1) ? e : 0.f;

        // rare fallback: runs longer than 8 (P ~ 2e-4 per voxel)
        for (unsigned p = base + 8; p < s1; p++)
            s += __bfloat162float(srt[p]);

        ob[v] = __fdividef(s, fmaxf((float)(s1 - s0), 1.0f));
    }
}

extern "C" void kernel_launch(void* const* d_in, const int* in_sizes, int n_in,
                              void* d_out, int out_size, void* d_ws, size_t ws_size,
                              hipStream_t stream) {
    const float* feats  = (const float*)d_in[0];   // [B,C,N]
    const float* coords = (const float*)d_in[1];   // [B,3,N]
    // d_in[2] = resolution (32), hardcoded.

    float* out_vox  = (float*)d_out;                     // B*C*R3
    float* out_norm = out_vox + (size_t)BB * CC * R3;    // B*3*N

    char* ws = (char*)d_ws;
    unsigned int* ghist  = (unsigned int*)ws;                    // 2 MB
    unsigned int* packed = (unsigned int*)(ws + (2 << 20));      // 2 MB (becomes pos)
    unsigned int* off    = (unsigned int*)(ws + (4 << 20));      // 1 MB

    points_kernel<<<BB * NSUB, 1024, 0, stream>>>(coords, out_norm, packed, ghist);
    scan_kernel<<<BB, 1024, 0, stream>>>(ghist, off);
    pos_kernel<<<(BB * NN / 4) / 256, 256, 0, stream>>>(packed, off, ghist);
    gather_kernel<<<dim3(CC, BB), 1024, 0, stream>>>(feats, packed, off, out_vox);
}